// Round 2
// baseline (29.165 us; speedup 1.0000x reference)
//
#include <hip/hip_runtime.h>

#define DELTA 10.0f
#define K2_BLOCKS 512
#define TI 256
#define TJ 128

// ---------- Kernel 1: compact pred into pos/neg lists via wave ballot ----------
__global__ void __launch_bounds__(256)
compact_kernel(const float* __restrict__ pred, const int* __restrict__ target,
               int B, unsigned* __restrict__ cnt,
               float* __restrict__ pos_buf, float* __restrict__ neg_buf) {
    const int i = blockIdx.x * 256 + threadIdx.x;
    const int lane = threadIdx.x & 63;
    float x = 0.0f;
    int t = -1;
    if (i < B) { x = pred[i]; t = target[i]; }
    const bool isPos = (t == 1);
    const bool isNeg = (t == 0);
    const unsigned long long mpos = __ballot(isPos);
    const unsigned long long mneg = __ballot(isNeg);
    const unsigned long long lm = (1ull << lane) - 1ull;
    const int ppre = __popcll(mpos & lm);
    const int npre = __popcll(mneg & lm);
    int pbase = 0, nbase = 0;
    if (lane == 0) {
        pbase = (int)atomicAdd(&cnt[0], (unsigned)__popcll(mpos));
        nbase = (int)atomicAdd(&cnt[1], (unsigned)__popcll(mneg));
    }
    pbase = __shfl(pbase, 0);
    nbase = __shfl(nbase, 0);
    if (isPos) pos_buf[pbase + ppre] = x;
    if (isNeg) neg_buf[nbase + npre] = x;
}

// ---------- Kernel 2: pairwise over pos x neg: count (x>y), clip correction ----------
__global__ void __launch_bounds__(256)
pair_kernel(const float* __restrict__ pos_buf, const float* __restrict__ neg_buf,
            const unsigned* __restrict__ cnt,
            unsigned* __restrict__ tc_part, float* __restrict__ corr_part) {
    __shared__ float yj[TJ];
    __shared__ unsigned stc[256];
    __shared__ float scr[256];
    const int tid = threadIdx.x;
    const int P  = (int)cnt[0];
    const int Nn = (int)cnt[1];
    const int nTi = (P + TI - 1) / TI;
    const int nTj = (Nn + TJ - 1) / TJ;
    const int nT = nTi * nTj;

    unsigned tc = 0;
    float corr = 0.0f;

    for (int t = blockIdx.x; t < nT; t += gridDim.x) {
        const int bi = t / nTj;
        const int bj = t % nTj;
        const int j0 = bj * TJ;
        const int jCount = min(TJ, Nn - j0);
        __syncthreads();  // protect yj across tiles
        if (tid < TJ && (j0 + tid) < Nn) yj[tid] = neg_buf[j0 + tid];
        __syncthreads();
        const int i = bi * TI + tid;
        if (i < P) {
            const float x  = pos_buf[i];
            const float xx = DELTA + x;
            #pragma unroll 8
            for (int jj = 0; jj < jCount; ++jj) {
                const float y = yj[jj];
                tc += (x > y) ? 1u : 0u;
                const float d  = xx - y;
                const float dm = fminf(d, 0.0f);     // nonzero only if hinge clips
                corr = fmaf(dm, dm, corr);           // subtract later from closed form
            }
        }
    }

    stc[tid] = tc;
    scr[tid] = corr;
    __syncthreads();
    for (int s = 128; s > 0; s >>= 1) {
        if (tid < s) { stc[tid] += stc[tid + s]; scr[tid] += scr[tid + s]; }
        __syncthreads();
    }
    if (tid == 0) {
        tc_part[blockIdx.x]   = stc[0];
        corr_part[blockIdx.x] = scr[0];
    }
}

// ---------- Kernel 3: moments over original array (deterministic) + combine ----------
__global__ void __launch_bounds__(256)
finalize_kernel(const float* __restrict__ pred, const int* __restrict__ target,
                int B, const unsigned* __restrict__ cnt,
                const unsigned* __restrict__ tc_part,
                const float* __restrict__ corr_part, int nParts,
                float* __restrict__ out) {
    __shared__ double r0[256], r1[256], r2[256], r3[256], r4[256], r5[256];
    const int tid = threadIdx.x;
    double tc = 0.0, corr = 0.0, a1 = 0.0, a2 = 0.0, s1 = 0.0, s2 = 0.0;
    for (int k = tid; k < nParts; k += 256) {
        tc   += (double)tc_part[k];
        corr += (double)corr_part[k];
    }
    for (int i = tid; i < B; i += 256) {
        const double x = (double)pred[i];
        const int t = target[i];
        if (t == 1) { const double xx = 10.0 + x; a1 += xx; a2 += xx * xx; }
        else if (t == 0) { s1 += x; s2 += x * x; }
    }
    r0[tid] = tc; r1[tid] = corr; r2[tid] = a1;
    r3[tid] = a2; r4[tid] = s1;   r5[tid] = s2;
    __syncthreads();
    for (int s = 128; s > 0; s >>= 1) {
        if (tid < s) {
            r0[tid] += r0[tid + s]; r1[tid] += r1[tid + s];
            r2[tid] += r2[tid + s]; r3[tid] += r3[tid + s];
            r4[tid] += r4[tid + s]; r5[tid] += r5[tid + s];
        }
        __syncthreads();
    }
    if (tid == 0) {
        const double P  = (double)cnt[0];
        const double Nn = (double)cnt[1];
        // sum over (pos,neg) of max(10+x-y,0)^2 = Nn*A2 - 2*A1*S1 + P*S2 - corr
        const double lossSum = Nn * r3[0] - 2.0 * r2[0] * r4[0] + P * r5[0] - r1[0];
        const double Npairs = P * Nn;
        out[0] = (float)(lossSum / Npairs);
        out[1] = (float)(r0[0] / Npairs);
    }
}

extern "C" void kernel_launch(void* const* d_in, const int* in_sizes, int n_in,
                              void* d_out, int out_size, void* d_ws, size_t ws_size,
                              hipStream_t stream) {
    const float* pred = (const float*)d_in[0];
    const int* target = (const int*)d_in[1];
    const int B = in_sizes[0];

    char* ws = (char*)d_ws;
    unsigned* cnt       = (unsigned*)(ws + 0);        // 8 B, zeroed each call
    unsigned* tc_part   = (unsigned*)(ws + 64);       // 512 * 4 B
    float*    corr_part = (float*)(ws + 64 + K2_BLOCKS * 4);
    float*    pos_buf   = (float*)(ws + 8192);
    float*    neg_buf   = pos_buf + B;

    hipMemsetAsync(cnt, 0, 64, stream);

    const int nb1 = (B + 255) / 256;
    compact_kernel<<<nb1, 256, 0, stream>>>(pred, target, B, cnt, pos_buf, neg_buf);
    pair_kernel<<<K2_BLOCKS, 256, 0, stream>>>(pos_buf, neg_buf, cnt, tc_part, corr_part);
    finalize_kernel<<<1, 256, 0, stream>>>(pred, target, B, cnt, tc_part, corr_part,
                                           K2_BLOCKS, (float*)d_out);
}

// Round 3
// 21.748 us; speedup vs baseline: 1.3410x; 1.3410x over previous
//
#include <hip/hip_runtime.h>

#define TILE 256

// ---------------- Kernel 1: pairwise T-count + clip correction ----------------
// Encoding trick: u_i = x if pos else -1e30 ; v_j = y if neg else +1e30.
// (u_i > v_j) is true exactly for (pos,neg) pairs with x > y.
// For the hinge-clip correction: xx_i = 10+x if pos else +1e30 ;
// w_j = y if neg else -1e30 ; dm = min(xx - w, 0) is nonzero only for
// (pos,neg) pairs whose hinge clips (y > x+10). corr = sum dm^2.
__global__ void __launch_bounds__(TILE)
pair_kernel(const float* __restrict__ pred, const int* __restrict__ target,
            int B, int nTj,
            unsigned* __restrict__ tc_part, float* __restrict__ corr_part) {
    __shared__ float vsh[TILE];
    __shared__ float wsh[TILE];
    __shared__ float smax[4];
    __shared__ unsigned stc[4];
    __shared__ float scr[4];

    const int tid = threadIdx.x;
    const int bi = blockIdx.x / nTj;
    const int bj = blockIdx.x % nTj;

    // ---- stage j tile ----
    const int jg = bj * TILE + tid;
    float vj = 1e30f, wj = -1e30f;
    if (jg < B) {
        const float y = pred[jg];
        if (target[jg] == 0) { vj = y; wj = y; }
    }
    vsh[tid] = vj;
    wsh[tid] = wj;

    // wave-level max of wj, then block max via 4 leaders
    float wmax = wj;
    #pragma unroll
    for (int off = 32; off > 0; off >>= 1)
        wmax = fmaxf(wmax, __shfl_xor(wmax, off));
    if ((tid & 63) == 0) smax[tid >> 6] = wmax;
    __syncthreads();
    const float tileMax = fmaxf(fmaxf(smax[0], smax[1]), fmaxf(smax[2], smax[3]));

    // ---- i element ----
    const int ig = bi * TILE + tid;
    float u = -1e30f, xx = 1e30f;
    if (ig < B) {
        const float x = pred[ig];
        if (target[ig] == 1) { u = x; xx = 10.0f + x; }
    }

    unsigned tc = 0;
    float corr = 0.0f;
    const float4* v4 = (const float4*)vsh;
    if (__all(xx >= tileMax)) {
        // fast path: no pair in this (wave, tile) can clip the hinge
        #pragma unroll 8
        for (int jj = 0; jj < TILE / 4; ++jj) {
            const float4 vv = v4[jj];
            tc += (u > vv.x);
            tc += (u > vv.y);
            tc += (u > vv.z);
            tc += (u > vv.w);
        }
    } else {
        const float4* w4 = (const float4*)wsh;
        #pragma unroll 4
        for (int jj = 0; jj < TILE / 4; ++jj) {
            const float4 vv = v4[jj];
            const float4 ww = w4[jj];
            float dm;
            tc += (u > vv.x); dm = fminf(xx - ww.x, 0.0f); corr = fmaf(dm, dm, corr);
            tc += (u > vv.y); dm = fminf(xx - ww.y, 0.0f); corr = fmaf(dm, dm, corr);
            tc += (u > vv.z); dm = fminf(xx - ww.z, 0.0f); corr = fmaf(dm, dm, corr);
            tc += (u > vv.w); dm = fminf(xx - ww.w, 0.0f); corr = fmaf(dm, dm, corr);
        }
    }

    // block reduce: 6-step wave butterfly + 4 leaders through LDS
    #pragma unroll
    for (int off = 32; off > 0; off >>= 1) {
        tc += __shfl_xor(tc, off);
        corr += __shfl_xor(corr, off);
    }
    if ((tid & 63) == 0) { stc[tid >> 6] = tc; scr[tid >> 6] = corr; }
    __syncthreads();
    if (tid == 0) {
        tc_part[blockIdx.x]   = stc[0] + stc[1] + stc[2] + stc[3];
        corr_part[blockIdx.x] = scr[0] + scr[1] + scr[2] + scr[3];
    }
}

// ---------------- Kernel 2: moments + counts + combine (deterministic) ----------------
__global__ void __launch_bounds__(256)
finalize_kernel(const float* __restrict__ pred, const int* __restrict__ target,
                int B, const unsigned* __restrict__ tc_part,
                const float* __restrict__ corr_part, int nParts,
                float* __restrict__ out) {
    __shared__ double red[8][256];
    const int tid = threadIdx.x;
    double tc = 0.0, corr = 0.0, a1 = 0.0, a2 = 0.0, s1 = 0.0, s2 = 0.0;
    double P = 0.0, Nn = 0.0;
    for (int k = tid; k < nParts; k += 256) {
        tc   += (double)tc_part[k];
        corr += (double)corr_part[k];
    }
    for (int i = tid; i < B; i += 256) {
        const double x = (double)pred[i];
        const int t = target[i];
        if (t == 1) { const double z = 10.0 + x; a1 += z; a2 += z * z; P += 1.0; }
        else if (t == 0) { s1 += x; s2 += x * x; Nn += 1.0; }
    }
    red[0][tid] = tc; red[1][tid] = corr; red[2][tid] = a1; red[3][tid] = a2;
    red[4][tid] = s1; red[5][tid] = s2;   red[6][tid] = P;  red[7][tid] = Nn;
    __syncthreads();
    for (int s = 128; s > 0; s >>= 1) {
        if (tid < s) {
            #pragma unroll
            for (int a = 0; a < 8; ++a) red[a][tid] += red[a][tid + s];
        }
        __syncthreads();
    }
    if (tid == 0) {
        const double Pc = red[6][0], Nc = red[7][0];
        // sum over (pos,neg) of max(10+x-y,0)^2 = Nn*A2 - 2*A1*S1 + P*S2 - corr
        const double lossSum = Nc * red[3][0] - 2.0 * red[2][0] * red[4][0]
                             + Pc * red[5][0] - red[1][0];
        const double Np = Pc * Nc;
        out[0] = (float)(lossSum / Np);
        out[1] = (float)(red[0][0] / Np);
    }
}

extern "C" void kernel_launch(void* const* d_in, const int* in_sizes, int n_in,
                              void* d_out, int out_size, void* d_ws, size_t ws_size,
                              hipStream_t stream) {
    const float* pred = (const float*)d_in[0];
    const int* target = (const int*)d_in[1];
    const int B = in_sizes[0];

    const int NB = (B + TILE - 1) / TILE;
    const int nb = NB * NB;

    unsigned* tc_part = (unsigned*)d_ws;
    float* corr_part  = (float*)((char*)d_ws + (((size_t)nb * 4 + 255) & ~(size_t)255));

    pair_kernel<<<nb, TILE, 0, stream>>>(pred, target, B, NB, tc_part, corr_part);
    finalize_kernel<<<1, 256, 0, stream>>>(pred, target, B, tc_part, corr_part, nb,
                                           (float*)d_out);
}